// Round 5
// baseline (420.603 us; speedup 1.0000x reference)
//
#include <hip/hip_runtime.h>
#include <hip/hip_bf16.h>

// ---------------------------------------------------------------------------
// Transformer block, B=8 S=1024 H=768 NH=12 HD=64 I=3072.  fp32 in/out,
// bf16 MFMA internals.
// Round 5: attn_k rewritten barrier-free: K/V read directly from global
// (L1/L2-resident per head; staging+2 syncthreads deleted), LDS only for the
// per-wave P round-trip -> occupancy 39%->~100%.  GELU via sigmoid(__expf).
// GEMM engine unchanged from round 4 (attribution).
// ---------------------------------------------------------------------------

typedef __attribute__((ext_vector_type(8))) short bf16x8;
typedef __attribute__((ext_vector_type(4))) float f32x4;
typedef const __attribute__((address_space(3))) char* lds_cp;

#define MFMA16(a, b, c) __builtin_amdgcn_mfma_f32_16x16x32_bf16((a), (b), (c), 0, 0, 0)

// inline-asm LDS read: invisible to compiler alias analysis (no auto-vmcnt).
#define DSR(dst, addr, off) \
    asm volatile("ds_read_b128 %0, %1 offset:" #off : "=v"(dst) : "v"(addr))
#define WAITV4 asm volatile("s_waitcnt vmcnt(4)" ::: "memory")
#define WAITV0 asm volatile("s_waitcnt vmcnt(0)" ::: "memory")
#define WAITLG asm volatile("s_waitcnt lgkmcnt(0)" ::: "memory")
#define SCHEDB __builtin_amdgcn_sched_barrier(0)

__device__ inline short f2bf(float x) {
    __hip_bfloat16 h = __float2bfloat16(x);
    return *reinterpret_cast<short*>(&h);
}

__device__ inline void gload_lds16(const void* g, void* lds) {
    __builtin_amdgcn_global_load_lds(
        (const __attribute__((address_space(1))) unsigned int*)g,
        (__attribute__((address_space(3))) unsigned int*)lds,
        16, 0, 0);
}

// ---------------------------------------------------------------------------
// Weight prep: W fp32 [K,N] -> Wt bf16 [N,K]   (tiled transpose + cast)
// ---------------------------------------------------------------------------
__global__ __launch_bounds__(256) void transpose_w(
    const float* __restrict__ W, short* __restrict__ Wt, int K, int N) {
    __shared__ float tile[32][33];
    const int tx = threadIdx.x & 31, ty = threadIdx.x >> 5;  // ty 0..7
    const int n0 = blockIdx.x * 32, k0 = blockIdx.y * 32;
#pragma unroll
    for (int i = 0; i < 4; ++i)
        tile[ty + i * 8][tx] = W[(size_t)(k0 + ty + i * 8) * N + n0 + tx];
    __syncthreads();
#pragma unroll
    for (int i = 0; i < 4; ++i)
        Wt[(size_t)(n0 + ty + i * 8) * K + k0 + tx] = f2bf(tile[tx][ty + i * 8]);
}

// ---------------------------------------------------------------------------
// LayerNorm: fp32 [M,768] -> bf16 [M,768]   (one block per row)
// ---------------------------------------------------------------------------
__global__ __launch_bounds__(256) void ln_k(
    const float* __restrict__ x, const float* __restrict__ g,
    const float* __restrict__ b, short* __restrict__ out) {
    const int row = blockIdx.x;
    const int tid = threadIdx.x;
    const float* xr = x + (size_t)row * 768;
    float v[3];
    float s = 0.f, sq = 0.f;
#pragma unroll
    for (int i = 0; i < 3; ++i) {
        v[i] = xr[tid + i * 256];
        s += v[i];
        sq += v[i] * v[i];
    }
#pragma unroll
    for (int off = 32; off >= 1; off >>= 1) {
        s += __shfl_xor(s, off);
        sq += __shfl_xor(sq, off);
    }
    __shared__ float ss[4], ssq[4];
    const int wid = tid >> 6;
    if ((tid & 63) == 0) { ss[wid] = s; ssq[wid] = sq; }
    __syncthreads();
    s = ss[0] + ss[1] + ss[2] + ss[3];
    sq = ssq[0] + ssq[1] + ssq[2] + ssq[3];
    const float mean = s * (1.0f / 768.0f);
    const float var = sq * (1.0f / 768.0f) - mean * mean;  // biased
    const float rstd = rsqrtf(var + 1e-5f);
    short* outr = out + (size_t)row * 768;
#pragma unroll
    for (int i = 0; i < 3; ++i) {
        const int c = tid + i * 256;
        outr[c] = f2bf((v[i] - mean) * rstd * g[c] + b[c]);
    }
}

// ---------------------------------------------------------------------------
// GEMM engine:  C[M,N] = A[M,K](bf16) @ Wt[N,K]^T(bf16) + bias, fused epilogues.
// 128x128 tile, BK=32, 4 waves (2x2), wave = 64x64 out (4x4 16x16 frags).
// Iter t: asm-ds_read buf t%3 | stage tile min(t+2,NT-1) -> buf (t+2)%3 |
// vmcnt(4) | barrier | lgkm(0) | 16 MFMA | barrier.  (unchanged, round 4)
// ---------------------------------------------------------------------------
enum { MODE_BF16 = 0, MODE_QKV = 1, MODE_F32RES = 2, MODE_GELU = 3 };

template <int MODE>
__global__ __launch_bounds__(256) void gemm3p(
    const short* __restrict__ A, const short* __restrict__ Wt,
    const float* __restrict__ bias, const float* __restrict__ resid,
    float* __restrict__ outf, short* __restrict__ outh,
    short* __restrict__ Qo, short* __restrict__ Ko, short* __restrict__ Vto,
    int M, int N, int K) {
    __shared__ __attribute__((aligned(128))) short Al[3][4096];  // [buf][128*32]
    __shared__ __attribute__((aligned(128))) short Bl[3][4096];
    const int tid = threadIdx.x;
    const int lane = tid & 63;
    const int w = tid >> 6;          // 4 waves
    const int wm = w >> 1, wn = w & 1;
    const int m0 = blockIdx.x * 128, n0 = blockIdx.y * 128;

    f32x4 acc[4][4] = {};

    // ---- staging: linear LDS dest, pre-swizzled global source ----
    const int srow = tid >> 2;
    const int scol = ((tid & 3) * 8) ^ (((tid >> 2) & 3) << 3);
    const short* Abase = A + (size_t)(m0 + srow) * K + scol;
    const short* Bbase = Wt + (size_t)(n0 + srow) * K + scol;
    const size_t K64 = (size_t)K * 64;
    short* const AlF = &Al[0][0];
    short* const BlF = &Bl[0][0];

    auto stageT = [&](int boS, int k0s) {  // boS: buffer offset in shorts
        gload_lds16(Abase + k0s,       AlF + boS + w * 512);
        gload_lds16(Abase + K64 + k0s, AlF + boS + 2048 + w * 512);
        gload_lds16(Bbase + k0s,       BlF + boS + w * 512);
        gload_lds16(Bbase + K64 + k0s, BlF + boS + 2048 + w * 512);
    };

    // ---- fragment read offsets (swizzled), bytes within one buffer ----
    const int lrow = lane & 15;
    const int lcolswz = ((lane >> 4) * 16) ^ ((lane & 3) << 4);
    const int aoff = wm * 4096 + lrow * 64 + lcolswz;
    const int boff = wn * 4096 + lrow * 64 + lcolswz;
    const lds_cp AlB = (lds_cp)AlF;
    const lds_cp BlB = (lds_cp)BlF;

    const int NT = K >> 5;

    // prologue: stage tiles 0,1; retire tile 0; collective barrier
    stageT(0, 0);
    stageT(4096, 32);
    WAITV4;
    SCHEDB;
    __builtin_amdgcn_s_barrier();

    int bo = 0, bo1 = 8192, bo2 = 16384;  // byte offsets of buffers t, t+1, t+2
    for (int t = 0; t < NT; ++t) {
        const lds_cp Ab = AlB + (bo + aoff);
        const lds_cp Bb = BlB + (bo + boff);
        bf16x8 av0, av1, av2, av3, bv0, bv1, bv2, bv3;
        DSR(av0, Ab, 0);
        DSR(av1, Ab, 1024);
        DSR(av2, Ab, 2048);
        DSR(av3, Ab, 3072);
        DSR(bv0, Bb, 0);
        DSR(bv1, Bb, 1024);
        DSR(bv2, Bb, 2048);
        DSR(bv3, Bb, 3072);

        int ts = t + 2;
        if (ts > NT - 1) ts = NT - 1;      // uniform dummy stage at tail
        stageT(bo2 >> 1, ts << 5);
        WAITV4;                             // tile t+1 landed; t+2 in flight
        SCHEDB;
        __builtin_amdgcn_s_barrier();
        WAITLG;                             // frags in VGPRs
        SCHEDB;                             // rule #18: pin MFMA after the wait

        __builtin_amdgcn_s_setprio(1);
        {
            bf16x8 av[4] = {av0, av1, av2, av3};
            bf16x8 bv[4] = {bv0, bv1, bv2, bv3};
#pragma unroll
            for (int mi = 0; mi < 4; ++mi)
#pragma unroll
                for (int ni = 0; ni < 4; ++ni)
                    acc[mi][ni] = MFMA16(av[mi], bv[ni], acc[mi][ni]);
        }
        __builtin_amdgcn_s_setprio(0);
        __builtin_amdgcn_s_barrier();

        const int tmp = bo; bo = bo1; bo1 = bo2; bo2 = tmp;
    }
    WAITV0;  // drain dummy stages before epilogue/endpgm

    // Epilogue.  C/D frag layout: col = lane&15, row = (lane>>4)*4 + r.
#pragma unroll
    for (int mi = 0; mi < 4; ++mi) {
#pragma unroll
        for (int ni = 0; ni < 4; ++ni) {
#pragma unroll
            for (int r = 0; r < 4; ++r) {
                const int row = m0 + wm * 64 + mi * 16 + (lane >> 4) * 4 + r;
                const int col = n0 + wn * 64 + ni * 16 + (lane & 15);
                float v = acc[mi][ni][r] + bias[col];
                if constexpr (MODE == MODE_BF16) {
                    outh[(size_t)row * N + col] = f2bf(v);
                } else if constexpr (MODE == MODE_GELU) {
                    // 0.5v(1+tanh(u)) == v*sigmoid(2u)
                    const float u = 0.7978845608028654f * (v + 0.044715f * v * v * v);
                    const float gl = v / (1.0f + __expf(-2.0f * u));
                    outh[(size_t)row * N + col] = f2bf(gl);
                } else if constexpr (MODE == MODE_F32RES) {
                    outf[(size_t)row * N + col] = v + resid[(size_t)row * N + col];
                } else {  // MODE_QKV: scatter into Q[B,NH,S,HD], K[B,NH,S,HD], Vt[B,NH,HD,S]
                    const int bb = row >> 10, s = row & 1023;
                    if (col < 768) {
                        const int hh = col >> 6, d = col & 63;
                        Qo[(((size_t)(bb * 12 + hh)) * 1024 + s) * 64 + d] = f2bf(v);
                    } else if (col < 1536) {
                        const int c2 = col - 768;
                        const int hh = c2 >> 6, d = c2 & 63;
                        Ko[(((size_t)(bb * 12 + hh)) * 1024 + s) * 64 + d] = f2bf(v);
                    } else {
                        const int c2 = col - 1536;
                        const int hh = c2 >> 6, d = c2 & 63;
                        Vto[(((size_t)(bb * 12 + hh)) * 64 + d) * 1024 + s] = f2bf(v);
                    }
                }
            }
        }
    }
}

// ---------------------------------------------------------------------------
// Flash attention, barrier-free.  Grid: B*NH*16 blocks; 4 waves, 16 q-rows
// each.  K/V fragments read DIRECTLY from global (per-head K/V = 256KB,
// L1/L2-resident; all 4 waves read identical K/V addresses -> L1 reuse).
// No __syncthreads anywhere; LDS only the per-wave P round-trip.
// ---------------------------------------------------------------------------
__global__ __launch_bounds__(256) void attn_k(
    const short* __restrict__ Q, const short* __restrict__ Kg,
    const short* __restrict__ Vtg, short* __restrict__ out) {
    __shared__ __attribute__((aligned(128))) short Pl[4][16 * 80];
    const int tid = threadIdx.x, lane = tid & 63, w = tid >> 6;
    const int bid = blockIdx.x;
    const int qt = bid & 15, bh = bid >> 4;
    const int b = bh / 12, h = bh % 12;
    const int q0 = qt * 64 + w * 16;

    // Q fragments (A-operand: row = lane&15, k = kk*32 + (lane>>4)*8 + j)
    bf16x8 aq[2];
    const short* Qb = Q + ((size_t)bh * 1024 + q0) * 64;
#pragma unroll
    for (int kk = 0; kk < 2; ++kk)
        aq[kk] = *(const bf16x8*)&Qb[(size_t)(lane & 15) * 64 + kk * 32 + (lane >> 4) * 8];

    float m_run[4], l_run[4];
    f32x4 o[4] = {};
#pragma unroll
    for (int r = 0; r < 4; ++r) { m_run[r] = -1e30f; l_run[r] = 0.f; }

    const short* Kb = Kg + (size_t)bh * 1024 * 64;   // [S,HD] rows contiguous
    const short* Vb = Vtg + (size_t)bh * 64 * 1024;  // [HD,S] rows contiguous

    const int klane = (lane & 15) * 64 + (lane >> 4) * 8;   // K frag offset
    const int vrow = lane & 15, vcol = (lane >> 4) * 8;     // V frag pieces

    for (int kv0 = 0; kv0 < 1024; kv0 += 64) {
        // scores: 16 q-rows x 64 kv   (K B-frags straight from global/L1)
        const short* Kt = Kb + (size_t)kv0 * 64;
        f32x4 sc[4];
#pragma unroll
        for (int nk = 0; nk < 4; ++nk) {
            const bf16x8 kb0 = *(const bf16x8*)&Kt[nk * 1024 + klane];
            const bf16x8 kb1 = *(const bf16x8*)&Kt[nk * 1024 + klane + 32];
            f32x4 z = {};
            z = MFMA16(aq[0], kb0, z);
            z = MFMA16(aq[1], kb1, z);
            sc[nk] = z * 0.125f;  // 1/sqrt(64)
        }

        // online softmax (row = (lane>>4)*4 + r; 16 cols across lane group)
        float alpha[4], padd[4][4];
#pragma unroll
        for (int r = 0; r < 4; ++r) {
            float ml = fmaxf(fmaxf(sc[0][r], sc[1][r]), fmaxf(sc[2][r], sc[3][r]));
#pragma unroll
            for (int mk = 1; mk <= 8; mk <<= 1) ml = fmaxf(ml, __shfl_xor(ml, mk));
            const float mn = fmaxf(m_run[r], ml);
            alpha[r] = __expf(m_run[r] - mn);
            m_run[r] = mn;
            float rsum = 0.f;
#pragma unroll
            for (int nk = 0; nk < 4; ++nk) {
                padd[nk][r] = __expf(sc[nk][r] - mn);
                rsum += padd[nk][r];
            }
#pragma unroll
            for (int mk = 1; mk <= 8; mk <<= 1) rsum += __shfl_xor(rsum, mk);
            l_run[r] = l_run[r] * alpha[r] + rsum;
#pragma unroll
            for (int dn = 0; dn < 4; ++dn) o[dn][r] *= alpha[r];
        }

        // P (C-layout) -> per-wave LDS -> A-layout fragments (same-wave RAW,
        // compiler's lgkmcnt ordering suffices; no barrier).
#pragma unroll
        for (int nk = 0; nk < 4; ++nk)
#pragma unroll
            for (int r = 0; r < 4; ++r)
                Pl[w][((lane >> 4) * 4 + r) * 80 + nk * 16 + (lane & 15)] = f2bf(padd[nk][r]);
        bf16x8 pa[2];
#pragma unroll
        for (int kk = 0; kk < 2; ++kk)
            pa[kk] = *(const bf16x8*)&Pl[w][(lane & 15) * 80 + kk * 32 + (lane >> 4) * 8];

        // PV: o[16 x 64d] += P[16 x 64kv] @ V[64kv x 64d]  (V frags from global)
#pragma unroll
        for (int dn = 0; dn < 4; ++dn) {
            const short* Vt0 = Vb + (size_t)(dn * 16 + vrow) * 1024 + kv0 + vcol;
            const bf16x8 bv0 = *(const bf16x8*)&Vt0[0];
            const bf16x8 bv1 = *(const bf16x8*)&Vt0[32];
            o[dn] = MFMA16(pa[0], bv0, o[dn]);
            o[dn] = MFMA16(pa[1], bv1, o[dn]);
        }
    }

    // normalize + write attn output as [B,S,H] bf16
#pragma unroll
    for (int dn = 0; dn < 4; ++dn)
#pragma unroll
        for (int r = 0; r < 4; ++r) {
            const int srow = q0 + (lane >> 4) * 4 + r;
            const float v = o[dn][r] / l_run[r];
            out[((size_t)(b * 1024) + srow) * 768 + h * 64 + dn * 16 + (lane & 15)] = f2bf(v);
        }
}

// ---------------------------------------------------------------------------
// Launch
// ---------------------------------------------------------------------------
extern "C" void kernel_launch(void* const* d_in, const int* in_sizes, int n_in,
                              void* d_out, int out_size, void* d_ws, size_t ws_size,
                              hipStream_t stream) {
    const float* x      = (const float*)d_in[0];
    const float* ln1_g  = (const float*)d_in[1];
    const float* ln1_b  = (const float*)d_in[2];
    const float* qkv_w  = (const float*)d_in[3];
    const float* qkv_b  = (const float*)d_in[4];
    const float* proj_w = (const float*)d_in[5];
    const float* proj_b = (const float*)d_in[6];
    const float* ln2_g  = (const float*)d_in[7];
    const float* ln2_b  = (const float*)d_in[8];
    const float* fc1_w  = (const float*)d_in[9];
    const float* fc1_b  = (const float*)d_in[10];
    const float* fc2_w  = (const float*)d_in[11];
    const float* fc2_b  = (const float*)d_in[12];
    float* outp = (float*)d_out;

    char* ws = (char*)d_ws;
    size_t off = 0;
    auto alloc = [&](size_t bytes) {
        char* p = ws + off;
        off = (off + bytes + 255) & ~(size_t)255;
        return p;
    };
    short* wt_qkv  = (short*)alloc(2304ull * 768 * 2);
    short* wt_proj = (short*)alloc(768ull * 768 * 2);
    short* wt_fc1  = (short*)alloc(3072ull * 768 * 2);
    short* wt_fc2  = (short*)alloc(768ull * 3072 * 2);
    short* hbuf    = (short*)alloc(8192ull * 768 * 2);
    short* Qb      = (short*)alloc(8192ull * 768 * 2);   // [B,NH,S,HD]
    short* Kbuf    = (short*)alloc(8192ull * 768 * 2);   // [B,NH,S,HD]
    short* Vtb     = (short*)alloc(8192ull * 768 * 2);   // [B,NH,HD,S]
    short* attnb   = (short*)alloc(8192ull * 768 * 2);   // [B,S,H]
    float* x2      = (float*)alloc(8192ull * 768 * 4);   // fp32 residual stream
    short* mfc     = Qb;  // alias: fc1 output [8192,3072] over dead Q/K/Vt/attn
    (void)ws_size; (void)in_sizes; (void)n_in; (void)out_size;

    // weight prep
    transpose_w<<<dim3(2304 / 32, 768 / 32), 256, 0, stream>>>(qkv_w, wt_qkv, 768, 2304);
    transpose_w<<<dim3(768 / 32, 768 / 32), 256, 0, stream>>>(proj_w, wt_proj, 768, 768);
    transpose_w<<<dim3(3072 / 32, 768 / 32), 256, 0, stream>>>(fc1_w, wt_fc1, 768, 3072);
    transpose_w<<<dim3(768 / 32, 3072 / 32), 256, 0, stream>>>(fc2_w, wt_fc2, 3072, 768);

    // attention sublayer
    ln_k<<<8192, 256, 0, stream>>>(x, ln1_g, ln1_b, hbuf);
    gemm3p<MODE_QKV><<<dim3(64, 18), 256, 0, stream>>>(
        hbuf, wt_qkv, qkv_b, nullptr, nullptr, nullptr, Qb, Kbuf, Vtb, 8192, 2304, 768);
    attn_k<<<1536, 256, 0, stream>>>(Qb, Kbuf, Vtb, attnb);
    gemm3p<MODE_F32RES><<<dim3(64, 6), 256, 0, stream>>>(
        attnb, wt_proj, proj_b, x, x2, nullptr, nullptr, nullptr, nullptr, 8192, 768, 768);

    // MLP sublayer
    ln_k<<<8192, 256, 0, stream>>>(x2, ln2_g, ln2_b, hbuf);
    gemm3p<MODE_GELU><<<dim3(64, 24), 256, 0, stream>>>(
        hbuf, wt_fc1, fc1_b, nullptr, nullptr, mfc, nullptr, nullptr, nullptr, 8192, 3072, 768);
    gemm3p<MODE_F32RES><<<dim3(64, 6), 256, 0, stream>>>(
        mfc, wt_fc2, fc2_b, x2, outp, nullptr, nullptr, nullptr, nullptr, 8192, 768, 3072);
}

// Round 6
// 310.362 us; speedup vs baseline: 1.3552x; 1.3552x over previous
//
#include <hip/hip_runtime.h>
#include <hip/hip_bf16.h>

// ---------------------------------------------------------------------------
// Transformer block, B=8 S=1024 H=768 NH=12 HD=64 I=3072.  fp32 in/out,
// bf16 MFMA internals.
// Round 6: attn reverted to staged-LDS (r4) + two measured fixes:
//   (1) XCD head-chunk swizzle: each XCD owns 12 whole heads -> KV L2-resident
//       per XCD (was replicated across 8 XCDs, FETCH 104MB vs 37MB ideal).
//   (2) K/V/P LDS tiles: stride 64 shorts + XOR swizzle col^=(row&7)<<3 ->
//       b128 reads at the 8-lane/bank floor (was 4-way aliased), LDS 30->24KB.
// GEMM engine unchanged from round 4 (attribution).
// ---------------------------------------------------------------------------

typedef __attribute__((ext_vector_type(8))) short bf16x8;
typedef __attribute__((ext_vector_type(4))) float f32x4;
typedef const __attribute__((address_space(3))) char* lds_cp;

#define MFMA16(a, b, c) __builtin_amdgcn_mfma_f32_16x16x32_bf16((a), (b), (c), 0, 0, 0)

// inline-asm LDS read: invisible to compiler alias analysis (no auto-vmcnt).
#define DSR(dst, addr, off) \
    asm volatile("ds_read_b128 %0, %1 offset:" #off : "=v"(dst) : "v"(addr))
#define WAITV4 asm volatile("s_waitcnt vmcnt(4)" ::: "memory")
#define WAITV0 asm volatile("s_waitcnt vmcnt(0)" ::: "memory")
#define WAITLG asm volatile("s_waitcnt lgkmcnt(0)" ::: "memory")
#define SCHEDB __builtin_amdgcn_sched_barrier(0)

__device__ inline short f2bf(float x) {
    __hip_bfloat16 h = __float2bfloat16(x);
    return *reinterpret_cast<short*>(&h);
}

__device__ inline void gload_lds16(const void* g, void* lds) {
    __builtin_amdgcn_global_load_lds(
        (const __attribute__((address_space(1))) unsigned int*)g,
        (__attribute__((address_space(3))) unsigned int*)lds,
        16, 0, 0);
}

// ---------------------------------------------------------------------------
// Weight prep: W fp32 [K,N] -> Wt bf16 [N,K]   (tiled transpose + cast)
// ---------------------------------------------------------------------------
__global__ __launch_bounds__(256) void transpose_w(
    const float* __restrict__ W, short* __restrict__ Wt, int K, int N) {
    __shared__ float tile[32][33];
    const int tx = threadIdx.x & 31, ty = threadIdx.x >> 5;  // ty 0..7
    const int n0 = blockIdx.x * 32, k0 = blockIdx.y * 32;
#pragma unroll
    for (int i = 0; i < 4; ++i)
        tile[ty + i * 8][tx] = W[(size_t)(k0 + ty + i * 8) * N + n0 + tx];
    __syncthreads();
#pragma unroll
    for (int i = 0; i < 4; ++i)
        Wt[(size_t)(n0 + ty + i * 8) * K + k0 + tx] = f2bf(tile[tx][ty + i * 8]);
}

// ---------------------------------------------------------------------------
// LayerNorm: fp32 [M,768] -> bf16 [M,768]   (one block per row)
// ---------------------------------------------------------------------------
__global__ __launch_bounds__(256) void ln_k(
    const float* __restrict__ x, const float* __restrict__ g,
    const float* __restrict__ b, short* __restrict__ out) {
    const int row = blockIdx.x;
    const int tid = threadIdx.x;
    const float* xr = x + (size_t)row * 768;
    float v[3];
    float s = 0.f, sq = 0.f;
#pragma unroll
    for (int i = 0; i < 3; ++i) {
        v[i] = xr[tid + i * 256];
        s += v[i];
        sq += v[i] * v[i];
    }
#pragma unroll
    for (int off = 32; off >= 1; off >>= 1) {
        s += __shfl_xor(s, off);
        sq += __shfl_xor(sq, off);
    }
    __shared__ float ss[4], ssq[4];
    const int wid = tid >> 6;
    if ((tid & 63) == 0) { ss[wid] = s; ssq[wid] = sq; }
    __syncthreads();
    s = ss[0] + ss[1] + ss[2] + ss[3];
    sq = ssq[0] + ssq[1] + ssq[2] + ssq[3];
    const float mean = s * (1.0f / 768.0f);
    const float var = sq * (1.0f / 768.0f) - mean * mean;  // biased
    const float rstd = rsqrtf(var + 1e-5f);
    short* outr = out + (size_t)row * 768;
#pragma unroll
    for (int i = 0; i < 3; ++i) {
        const int c = tid + i * 256;
        outr[c] = f2bf((v[i] - mean) * rstd * g[c] + b[c]);
    }
}

// ---------------------------------------------------------------------------
// GEMM engine:  C[M,N] = A[M,K](bf16) @ Wt[N,K]^T(bf16) + bias, fused epilogues.
// 128x128 tile, BK=32, 4 waves (2x2), wave = 64x64 out (4x4 16x16 frags).
// Iter t: asm-ds_read buf t%3 | stage tile min(t+2,NT-1) -> buf (t+2)%3 |
// vmcnt(4) | barrier | lgkm(0) | 16 MFMA | barrier.  (unchanged, round 4)
// ---------------------------------------------------------------------------
enum { MODE_BF16 = 0, MODE_QKV = 1, MODE_F32RES = 2, MODE_GELU = 3 };

template <int MODE>
__global__ __launch_bounds__(256) void gemm3p(
    const short* __restrict__ A, const short* __restrict__ Wt,
    const float* __restrict__ bias, const float* __restrict__ resid,
    float* __restrict__ outf, short* __restrict__ outh,
    short* __restrict__ Qo, short* __restrict__ Ko, short* __restrict__ Vto,
    int M, int N, int K) {
    __shared__ __attribute__((aligned(128))) short Al[3][4096];  // [buf][128*32]
    __shared__ __attribute__((aligned(128))) short Bl[3][4096];
    const int tid = threadIdx.x;
    const int lane = tid & 63;
    const int w = tid >> 6;          // 4 waves
    const int wm = w >> 1, wn = w & 1;
    const int m0 = blockIdx.x * 128, n0 = blockIdx.y * 128;

    f32x4 acc[4][4] = {};

    // ---- staging: linear LDS dest, pre-swizzled global source ----
    const int srow = tid >> 2;
    const int scol = ((tid & 3) * 8) ^ (((tid >> 2) & 3) << 3);
    const short* Abase = A + (size_t)(m0 + srow) * K + scol;
    const short* Bbase = Wt + (size_t)(n0 + srow) * K + scol;
    const size_t K64 = (size_t)K * 64;
    short* const AlF = &Al[0][0];
    short* const BlF = &Bl[0][0];

    auto stageT = [&](int boS, int k0s) {  // boS: buffer offset in shorts
        gload_lds16(Abase + k0s,       AlF + boS + w * 512);
        gload_lds16(Abase + K64 + k0s, AlF + boS + 2048 + w * 512);
        gload_lds16(Bbase + k0s,       BlF + boS + w * 512);
        gload_lds16(Bbase + K64 + k0s, BlF + boS + 2048 + w * 512);
    };

    // ---- fragment read offsets (swizzled), bytes within one buffer ----
    const int lrow = lane & 15;
    const int lcolswz = ((lane >> 4) * 16) ^ ((lane & 3) << 4);
    const int aoff = wm * 4096 + lrow * 64 + lcolswz;
    const int boff = wn * 4096 + lrow * 64 + lcolswz;
    const lds_cp AlB = (lds_cp)AlF;
    const lds_cp BlB = (lds_cp)BlF;

    const int NT = K >> 5;

    // prologue: stage tiles 0,1; retire tile 0; collective barrier
    stageT(0, 0);
    stageT(4096, 32);
    WAITV4;
    SCHEDB;
    __builtin_amdgcn_s_barrier();

    int bo = 0, bo1 = 8192, bo2 = 16384;  // byte offsets of buffers t, t+1, t+2
    for (int t = 0; t < NT; ++t) {
        const lds_cp Ab = AlB + (bo + aoff);
        const lds_cp Bb = BlB + (bo + boff);
        bf16x8 av0, av1, av2, av3, bv0, bv1, bv2, bv3;
        DSR(av0, Ab, 0);
        DSR(av1, Ab, 1024);
        DSR(av2, Ab, 2048);
        DSR(av3, Ab, 3072);
        DSR(bv0, Bb, 0);
        DSR(bv1, Bb, 1024);
        DSR(bv2, Bb, 2048);
        DSR(bv3, Bb, 3072);

        int ts = t + 2;
        if (ts > NT - 1) ts = NT - 1;      // uniform dummy stage at tail
        stageT(bo2 >> 1, ts << 5);
        WAITV4;                             // tile t+1 landed; t+2 in flight
        SCHEDB;
        __builtin_amdgcn_s_barrier();
        WAITLG;                             // frags in VGPRs
        SCHEDB;                             // rule #18: pin MFMA after the wait

        __builtin_amdgcn_s_setprio(1);
        {
            bf16x8 av[4] = {av0, av1, av2, av3};
            bf16x8 bv[4] = {bv0, bv1, bv2, bv3};
#pragma unroll
            for (int mi = 0; mi < 4; ++mi)
#pragma unroll
                for (int ni = 0; ni < 4; ++ni)
                    acc[mi][ni] = MFMA16(av[mi], bv[ni], acc[mi][ni]);
        }
        __builtin_amdgcn_s_setprio(0);
        __builtin_amdgcn_s_barrier();

        const int tmp = bo; bo = bo1; bo1 = bo2; bo2 = tmp;
    }
    WAITV0;  // drain dummy stages before epilogue/endpgm

    // Epilogue.  C/D frag layout: col = lane&15, row = (lane>>4)*4 + r.
#pragma unroll
    for (int mi = 0; mi < 4; ++mi) {
#pragma unroll
        for (int ni = 0; ni < 4; ++ni) {
#pragma unroll
            for (int r = 0; r < 4; ++r) {
                const int row = m0 + wm * 64 + mi * 16 + (lane >> 4) * 4 + r;
                const int col = n0 + wn * 64 + ni * 16 + (lane & 15);
                float v = acc[mi][ni][r] + bias[col];
                if constexpr (MODE == MODE_BF16) {
                    outh[(size_t)row * N + col] = f2bf(v);
                } else if constexpr (MODE == MODE_GELU) {
                    // 0.5v(1+tanh(u)) == v*sigmoid(2u)
                    const float u = 0.7978845608028654f * (v + 0.044715f * v * v * v);
                    const float gl = v / (1.0f + __expf(-2.0f * u));
                    outh[(size_t)row * N + col] = f2bf(gl);
                } else if constexpr (MODE == MODE_F32RES) {
                    outf[(size_t)row * N + col] = v + resid[(size_t)row * N + col];
                } else {  // MODE_QKV: scatter into Q[B,NH,S,HD], K[B,NH,S,HD], Vt[B,NH,HD,S]
                    const int bb = row >> 10, s = row & 1023;
                    if (col < 768) {
                        const int hh = col >> 6, d = col & 63;
                        Qo[(((size_t)(bb * 12 + hh)) * 1024 + s) * 64 + d] = f2bf(v);
                    } else if (col < 1536) {
                        const int c2 = col - 768;
                        const int hh = c2 >> 6, d = c2 & 63;
                        Ko[(((size_t)(bb * 12 + hh)) * 1024 + s) * 64 + d] = f2bf(v);
                    } else {
                        const int c2 = col - 1536;
                        const int hh = c2 >> 6, d = c2 & 63;
                        Vto[(((size_t)(bb * 12 + hh)) * 64 + d) * 1024 + s] = f2bf(v);
                    }
                }
            }
        }
    }
}

// ---------------------------------------------------------------------------
// Flash attention (staged LDS, r4 structure).  Grid: B*NH*16 blocks, XCD-
// swizzled so each XCD owns 12 whole heads (KV L2-resident per XCD).
// 4 waves x 16 q-rows.  K/V/P tiles: [64][64] shorts, col ^= (row&7)<<3.
// ---------------------------------------------------------------------------
__global__ __launch_bounds__(256) void attn_k(
    const short* __restrict__ Q, const short* __restrict__ Kg,
    const short* __restrict__ Vtg, short* __restrict__ out) {
    __shared__ __attribute__((aligned(128))) short Kl[64 * 64];
    __shared__ __attribute__((aligned(128))) short Vl[64 * 64];
    __shared__ __attribute__((aligned(128))) short Pl[4][16 * 64];
    const int tid = threadIdx.x, lane = tid & 63, w = tid >> 6;
    // XCD chunk swizzle: 1536 blocks = 8 XCDs x 192; contiguous orig ids
    // (same head) land on one XCD.
    const int swz = (blockIdx.x & 7) * 192 + (blockIdx.x >> 3);
    const int qt = swz & 15, bh = swz >> 4;
    const int b = bh / 12, h = bh % 12;
    const int q0 = qt * 64 + w * 16;

    const int l15 = lane & 15, g = lane >> 4;

    // Q fragments (A-operand: row = lane&15, k = kk*32 + g*8 + j)
    bf16x8 aq[2];
    const short* Qb = Q + ((size_t)bh * 1024 + q0) * 64;
#pragma unroll
    for (int kk = 0; kk < 2; ++kk)
        aq[kk] = *(const bf16x8*)&Qb[(size_t)l15 * 64 + kk * 32 + g * 8];

    float m_run[4], l_run[4];
    f32x4 o[4] = {};
#pragma unroll
    for (int r = 0; r < 4; ++r) { m_run[r] = -1e30f; l_run[r] = 0.f; }

    const short* Kb = Kg + (size_t)bh * 1024 * 64;
    const short* Vb = Vtg + (size_t)bh * 64 * 1024;

    for (int kv0 = 0; kv0 < 1024; kv0 += 64) {
        // stage K,V tiles with XOR-swizzled columns
        for (int c = tid; c < 512; c += 256) {
            const int rr = c >> 3, pp = (c & 7) * 8;
            const int sc = pp ^ ((rr & 7) << 3);
            *(bf16x8*)&Kl[rr * 64 + sc] = *(const bf16x8*)&Kb[(size_t)(kv0 + rr) * 64 + pp];
            *(bf16x8*)&Vl[rr * 64 + sc] = *(const bf16x8*)&Vb[(size_t)rr * 1024 + kv0 + pp];
        }
        __syncthreads();

        // scores: 16 q-rows x 64 kv
        f32x4 sc4[4];
#pragma unroll
        for (int nk = 0; nk < 4; ++nk) {
            const int R = nk * 16 + l15;
            const int x = (R & 7) << 3;
            const bf16x8 kb0 = *(const bf16x8*)&Kl[R * 64 + ((g * 8) ^ x)];
            const bf16x8 kb1 = *(const bf16x8*)&Kl[R * 64 + ((32 + g * 8) ^ x)];
            f32x4 z = {};
            z = MFMA16(aq[0], kb0, z);
            z = MFMA16(aq[1], kb1, z);
            sc4[nk] = z * 0.125f;  // 1/sqrt(64)
        }

        // online softmax (row = g*4 + r; 16 cols across lanes 0..15 of group)
        float alpha[4], padd[4][4];
#pragma unroll
        for (int r = 0; r < 4; ++r) {
            float ml = fmaxf(fmaxf(sc4[0][r], sc4[1][r]), fmaxf(sc4[2][r], sc4[3][r]));
#pragma unroll
            for (int mk = 1; mk <= 8; mk <<= 1) ml = fmaxf(ml, __shfl_xor(ml, mk));
            const float mn = fmaxf(m_run[r], ml);
            alpha[r] = __expf(m_run[r] - mn);
            m_run[r] = mn;
            float rsum = 0.f;
#pragma unroll
            for (int nk = 0; nk < 4; ++nk) {
                padd[nk][r] = __expf(sc4[nk][r] - mn);
                rsum += padd[nk][r];
            }
#pragma unroll
            for (int mk = 1; mk <= 8; mk <<= 1) rsum += __shfl_xor(rsum, mk);
            l_run[r] = l_run[r] * alpha[r] + rsum;
#pragma unroll
            for (int dn = 0; dn < 4; ++dn) o[dn][r] *= alpha[r];
        }

        // P (C-layout) -> per-wave LDS -> A-layout fragments (swizzled)
#pragma unroll
        for (int nk = 0; nk < 4; ++nk)
#pragma unroll
            for (int r = 0; r < 4; ++r) {
                const int rr = g * 4 + r, cc = nk * 16 + l15;
                Pl[w][rr * 64 + (cc ^ ((rr & 7) << 3))] = f2bf(padd[nk][r]);
            }
        bf16x8 pa[2];
#pragma unroll
        for (int kk = 0; kk < 2; ++kk)
            pa[kk] = *(const bf16x8*)&Pl[w][l15 * 64 + ((kk * 32 + g * 8) ^ ((l15 & 7) << 3))];

        // PV: o[16 x 64d] += P[16 x 64kv] @ V[64kv x 64d]
#pragma unroll
        for (int dn = 0; dn < 4; ++dn) {
            const int R = dn * 16 + l15;
            const int x = (R & 7) << 3;
            const bf16x8 bv0 = *(const bf16x8*)&Vl[R * 64 + ((g * 8) ^ x)];
            const bf16x8 bv1 = *(const bf16x8*)&Vl[R * 64 + ((32 + g * 8) ^ x)];
            o[dn] = MFMA16(pa[0], bv0, o[dn]);
            o[dn] = MFMA16(pa[1], bv1, o[dn]);
        }
        __syncthreads();
    }

    // normalize + write attn output as [B,S,H] bf16
#pragma unroll
    for (int dn = 0; dn < 4; ++dn)
#pragma unroll
        for (int r = 0; r < 4; ++r) {
            const int srow = q0 + g * 4 + r;
            const float v = o[dn][r] / l_run[r];
            out[((size_t)(b * 1024) + srow) * 768 + h * 64 + dn * 16 + l15] = f2bf(v);
        }
}

// ---------------------------------------------------------------------------
// Launch
// ---------------------------------------------------------------------------
extern "C" void kernel_launch(void* const* d_in, const int* in_sizes, int n_in,
                              void* d_out, int out_size, void* d_ws, size_t ws_size,
                              hipStream_t stream) {
    const float* x      = (const float*)d_in[0];
    const float* ln1_g  = (const float*)d_in[1];
    const float* ln1_b  = (const float*)d_in[2];
    const float* qkv_w  = (const float*)d_in[3];
    const float* qkv_b  = (const float*)d_in[4];
    const float* proj_w = (const float*)d_in[5];
    const float* proj_b = (const float*)d_in[6];
    const float* ln2_g  = (const float*)d_in[7];
    const float* ln2_b  = (const float*)d_in[8];
    const float* fc1_w  = (const float*)d_in[9];
    const float* fc1_b  = (const float*)d_in[10];
    const float* fc2_w  = (const float*)d_in[11];
    const float* fc2_b  = (const float*)d_in[12];
    float* outp = (float*)d_out;

    char* ws = (char*)d_ws;
    size_t off = 0;
    auto alloc = [&](size_t bytes) {
        char* p = ws + off;
        off = (off + bytes + 255) & ~(size_t)255;
        return p;
    };
    short* wt_qkv  = (short*)alloc(2304ull * 768 * 2);
    short* wt_proj = (short*)alloc(768ull * 768 * 2);
    short* wt_fc1  = (short*)alloc(3072ull * 768 * 2);
    short* wt_fc2  = (short*)alloc(768ull * 3072 * 2);
    short* hbuf    = (short*)alloc(8192ull * 768 * 2);
    short* Qb      = (short*)alloc(8192ull * 768 * 2);   // [B,NH,S,HD]
    short* Kbuf    = (short*)alloc(8192ull * 768 * 2);   // [B,NH,S,HD]
    short* Vtb     = (short*)alloc(8192ull * 768 * 2);   // [B,NH,HD,S]
    short* attnb   = (short*)alloc(8192ull * 768 * 2);   // [B,S,H]
    float* x2      = (float*)alloc(8192ull * 768 * 4);   // fp32 residual stream
    short* mfc     = Qb;  // alias: fc1 output [8192,3072] over dead Q/K/Vt/attn
    (void)ws_size; (void)in_sizes; (void)n_in; (void)out_size;

    // weight prep
    transpose_w<<<dim3(2304 / 32, 768 / 32), 256, 0, stream>>>(qkv_w, wt_qkv, 768, 2304);
    transpose_w<<<dim3(768 / 32, 768 / 32), 256, 0, stream>>>(proj_w, wt_proj, 768, 768);
    transpose_w<<<dim3(3072 / 32, 768 / 32), 256, 0, stream>>>(fc1_w, wt_fc1, 768, 3072);
    transpose_w<<<dim3(768 / 32, 3072 / 32), 256, 0, stream>>>(fc2_w, wt_fc2, 3072, 768);

    // attention sublayer
    ln_k<<<8192, 256, 0, stream>>>(x, ln1_g, ln1_b, hbuf);
    gemm3p<MODE_QKV><<<dim3(64, 18), 256, 0, stream>>>(
        hbuf, wt_qkv, qkv_b, nullptr, nullptr, nullptr, Qb, Kbuf, Vtb, 8192, 2304, 768);
    attn_k<<<1536, 256, 0, stream>>>(Qb, Kbuf, Vtb, attnb);
    gemm3p<MODE_F32RES><<<dim3(64, 6), 256, 0, stream>>>(
        attnb, wt_proj, proj_b, x, x2, nullptr, nullptr, nullptr, nullptr, 8192, 768, 768);

    // MLP sublayer
    ln_k<<<8192, 256, 0, stream>>>(x2, ln2_g, ln2_b, hbuf);
    gemm3p<MODE_GELU><<<dim3(64, 24), 256, 0, stream>>>(
        hbuf, wt_fc1, fc1_b, nullptr, nullptr, mfc, nullptr, nullptr, nullptr, 8192, 3072, 768);
    gemm3p<MODE_F32RES><<<dim3(64, 6), 256, 0, stream>>>(
        mfc, wt_fc2, fc2_b, x2, outp, nullptr, nullptr, nullptr, nullptr, 8192, 768, 3072);
}

// Round 7
// 308.615 us; speedup vs baseline: 1.3629x; 1.0057x over previous
//
#include <hip/hip_runtime.h>
#include <hip/hip_bf16.h>

// ---------------------------------------------------------------------------
// Transformer block, B=8 S=1024 H=768 NH=12 HD=64 I=3072.  fp32 in/out,
// bf16 MFMA internals.
// Round 7: attn gets a 1-barrier-per-tile double-buffered K/V pipeline:
//   stage(t+1) via global_load_lds (pre-swizzled source) issued BEFORE
//   compute(t); K/V fragment reads are inline-asm ds_read_b128 (+lgkmcnt
//   +sched_barrier) so compiler alias analysis can't re-insert vmcnt(0).
//   1/sqrt(d) folded into Q at QKV epilogue; rcp in attn normalize.
// GEMM engine unchanged from round 4 (attribution).
// ---------------------------------------------------------------------------

typedef __attribute__((ext_vector_type(8))) short bf16x8;
typedef __attribute__((ext_vector_type(4))) float f32x4;
typedef const __attribute__((address_space(3))) char* lds_cp;

#define MFMA16(a, b, c) __builtin_amdgcn_mfma_f32_16x16x32_bf16((a), (b), (c), 0, 0, 0)

// inline-asm LDS read: invisible to compiler alias analysis (no auto-vmcnt).
#define DSR(dst, addr, off) \
    asm volatile("ds_read_b128 %0, %1 offset:" #off : "=v"(dst) : "v"(addr))
#define WAITV4 asm volatile("s_waitcnt vmcnt(4)" ::: "memory")
#define WAITV0 asm volatile("s_waitcnt vmcnt(0)" ::: "memory")
#define WAITLG asm volatile("s_waitcnt lgkmcnt(0)" ::: "memory")
#define SCHEDB __builtin_amdgcn_sched_barrier(0)

__device__ inline short f2bf(float x) {
    __hip_bfloat16 h = __float2bfloat16(x);
    return *reinterpret_cast<short*>(&h);
}

__device__ inline void gload_lds16(const void* g, void* lds) {
    __builtin_amdgcn_global_load_lds(
        (const __attribute__((address_space(1))) unsigned int*)g,
        (__attribute__((address_space(3))) unsigned int*)lds,
        16, 0, 0);
}

// ---------------------------------------------------------------------------
// Weight prep: W fp32 [K,N] -> Wt bf16 [N,K]   (tiled transpose + cast)
// ---------------------------------------------------------------------------
__global__ __launch_bounds__(256) void transpose_w(
    const float* __restrict__ W, short* __restrict__ Wt, int K, int N) {
    __shared__ float tile[32][33];
    const int tx = threadIdx.x & 31, ty = threadIdx.x >> 5;  // ty 0..7
    const int n0 = blockIdx.x * 32, k0 = blockIdx.y * 32;
#pragma unroll
    for (int i = 0; i < 4; ++i)
        tile[ty + i * 8][tx] = W[(size_t)(k0 + ty + i * 8) * N + n0 + tx];
    __syncthreads();
#pragma unroll
    for (int i = 0; i < 4; ++i)
        Wt[(size_t)(n0 + ty + i * 8) * K + k0 + tx] = f2bf(tile[tx][ty + i * 8]);
}

// ---------------------------------------------------------------------------
// LayerNorm: fp32 [M,768] -> bf16 [M,768]   (one block per row)
// ---------------------------------------------------------------------------
__global__ __launch_bounds__(256) void ln_k(
    const float* __restrict__ x, const float* __restrict__ g,
    const float* __restrict__ b, short* __restrict__ out) {
    const int row = blockIdx.x;
    const int tid = threadIdx.x;
    const float* xr = x + (size_t)row * 768;
    float v[3];
    float s = 0.f, sq = 0.f;
#pragma unroll
    for (int i = 0; i < 3; ++i) {
        v[i] = xr[tid + i * 256];
        s += v[i];
        sq += v[i] * v[i];
    }
#pragma unroll
    for (int off = 32; off >= 1; off >>= 1) {
        s += __shfl_xor(s, off);
        sq += __shfl_xor(sq, off);
    }
    __shared__ float ss[4], ssq[4];
    const int wid = tid >> 6;
    if ((tid & 63) == 0) { ss[wid] = s; ssq[wid] = sq; }
    __syncthreads();
    s = ss[0] + ss[1] + ss[2] + ss[3];
    sq = ssq[0] + ssq[1] + ssq[2] + ssq[3];
    const float mean = s * (1.0f / 768.0f);
    const float var = sq * (1.0f / 768.0f) - mean * mean;  // biased
    const float rstd = rsqrtf(var + 1e-5f);
    short* outr = out + (size_t)row * 768;
#pragma unroll
    for (int i = 0; i < 3; ++i) {
        const int c = tid + i * 256;
        outr[c] = f2bf((v[i] - mean) * rstd * g[c] + b[c]);
    }
}

// ---------------------------------------------------------------------------
// GEMM engine:  C[M,N] = A[M,K](bf16) @ Wt[N,K]^T(bf16) + bias, fused epilogues.
// 128x128 tile, BK=32, 4 waves (2x2), wave = 64x64 out (4x4 16x16 frags).
// (unchanged from round 4)
// ---------------------------------------------------------------------------
enum { MODE_BF16 = 0, MODE_QKV = 1, MODE_F32RES = 2, MODE_GELU = 3 };

template <int MODE>
__global__ __launch_bounds__(256) void gemm3p(
    const short* __restrict__ A, const short* __restrict__ Wt,
    const float* __restrict__ bias, const float* __restrict__ resid,
    float* __restrict__ outf, short* __restrict__ outh,
    short* __restrict__ Qo, short* __restrict__ Ko, short* __restrict__ Vto,
    int M, int N, int K) {
    __shared__ __attribute__((aligned(128))) short Al[3][4096];  // [buf][128*32]
    __shared__ __attribute__((aligned(128))) short Bl[3][4096];
    const int tid = threadIdx.x;
    const int lane = tid & 63;
    const int w = tid >> 6;          // 4 waves
    const int wm = w >> 1, wn = w & 1;
    const int m0 = blockIdx.x * 128, n0 = blockIdx.y * 128;

    f32x4 acc[4][4] = {};

    // ---- staging: linear LDS dest, pre-swizzled global source ----
    const int srow = tid >> 2;
    const int scol = ((tid & 3) * 8) ^ (((tid >> 2) & 3) << 3);
    const short* Abase = A + (size_t)(m0 + srow) * K + scol;
    const short* Bbase = Wt + (size_t)(n0 + srow) * K + scol;
    const size_t K64 = (size_t)K * 64;
    short* const AlF = &Al[0][0];
    short* const BlF = &Bl[0][0];

    auto stageT = [&](int boS, int k0s) {  // boS: buffer offset in shorts
        gload_lds16(Abase + k0s,       AlF + boS + w * 512);
        gload_lds16(Abase + K64 + k0s, AlF + boS + 2048 + w * 512);
        gload_lds16(Bbase + k0s,       BlF + boS + w * 512);
        gload_lds16(Bbase + K64 + k0s, BlF + boS + 2048 + w * 512);
    };

    // ---- fragment read offsets (swizzled), bytes within one buffer ----
    const int lrow = lane & 15;
    const int lcolswz = ((lane >> 4) * 16) ^ ((lane & 3) << 4);
    const int aoff = wm * 4096 + lrow * 64 + lcolswz;
    const int boff = wn * 4096 + lrow * 64 + lcolswz;
    const lds_cp AlB = (lds_cp)AlF;
    const lds_cp BlB = (lds_cp)BlF;

    const int NT = K >> 5;

    // prologue: stage tiles 0,1; retire tile 0; collective barrier
    stageT(0, 0);
    stageT(4096, 32);
    WAITV4;
    SCHEDB;
    __builtin_amdgcn_s_barrier();

    int bo = 0, bo1 = 8192, bo2 = 16384;  // byte offsets of buffers t, t+1, t+2
    for (int t = 0; t < NT; ++t) {
        const lds_cp Ab = AlB + (bo + aoff);
        const lds_cp Bb = BlB + (bo + boff);
        bf16x8 av0, av1, av2, av3, bv0, bv1, bv2, bv3;
        DSR(av0, Ab, 0);
        DSR(av1, Ab, 1024);
        DSR(av2, Ab, 2048);
        DSR(av3, Ab, 3072);
        DSR(bv0, Bb, 0);
        DSR(bv1, Bb, 1024);
        DSR(bv2, Bb, 2048);
        DSR(bv3, Bb, 3072);

        int ts = t + 2;
        if (ts > NT - 1) ts = NT - 1;      // uniform dummy stage at tail
        stageT(bo2 >> 1, ts << 5);
        WAITV4;                             // tile t+1 landed; t+2 in flight
        SCHEDB;
        __builtin_amdgcn_s_barrier();
        WAITLG;                             // frags in VGPRs
        SCHEDB;                             // rule #18: pin MFMA after the wait

        __builtin_amdgcn_s_setprio(1);
        {
            bf16x8 av[4] = {av0, av1, av2, av3};
            bf16x8 bv[4] = {bv0, bv1, bv2, bv3};
#pragma unroll
            for (int mi = 0; mi < 4; ++mi)
#pragma unroll
                for (int ni = 0; ni < 4; ++ni)
                    acc[mi][ni] = MFMA16(av[mi], bv[ni], acc[mi][ni]);
        }
        __builtin_amdgcn_s_setprio(0);
        __builtin_amdgcn_s_barrier();

        const int tmp = bo; bo = bo1; bo1 = bo2; bo2 = tmp;
    }
    WAITV0;  // drain dummy stages before epilogue/endpgm

    // Epilogue.  C/D frag layout: col = lane&15, row = (lane>>4)*4 + r.
#pragma unroll
    for (int mi = 0; mi < 4; ++mi) {
#pragma unroll
        for (int ni = 0; ni < 4; ++ni) {
#pragma unroll
            for (int r = 0; r < 4; ++r) {
                const int row = m0 + wm * 64 + mi * 16 + (lane >> 4) * 4 + r;
                const int col = n0 + wn * 64 + ni * 16 + (lane & 15);
                float v = acc[mi][ni][r] + bias[col];
                if constexpr (MODE == MODE_BF16) {
                    outh[(size_t)row * N + col] = f2bf(v);
                } else if constexpr (MODE == MODE_GELU) {
                    // 0.5v(1+tanh(u)) == v*sigmoid(2u)
                    const float u = 0.7978845608028654f * (v + 0.044715f * v * v * v);
                    const float gl = v / (1.0f + __expf(-2.0f * u));
                    outh[(size_t)row * N + col] = f2bf(gl);
                } else if constexpr (MODE == MODE_F32RES) {
                    outf[(size_t)row * N + col] = v + resid[(size_t)row * N + col];
                } else {  // MODE_QKV: scatter into Q[B,NH,S,HD] (pre-scaled by
                          // 1/sqrt(HD)), K[B,NH,S,HD], Vt[B,NH,HD,S]
                    const int bb = row >> 10, s = row & 1023;
                    if (col < 768) {
                        const int hh = col >> 6, d = col & 63;
                        Qo[(((size_t)(bb * 12 + hh)) * 1024 + s) * 64 + d] = f2bf(v * 0.125f);
                    } else if (col < 1536) {
                        const int c2 = col - 768;
                        const int hh = c2 >> 6, d = c2 & 63;
                        Ko[(((size_t)(bb * 12 + hh)) * 1024 + s) * 64 + d] = f2bf(v);
                    } else {
                        const int c2 = col - 1536;
                        const int hh = c2 >> 6, d = c2 & 63;
                        Vto[(((size_t)(bb * 12 + hh)) * 64 + d) * 1024 + s] = f2bf(v);
                    }
                }
            }
        }
    }
}

// ---------------------------------------------------------------------------
// Flash attention, double-buffered 1-barrier pipeline.
// Grid: B*NH*16 blocks, XCD-swizzled (each XCD owns 12 whole heads).
// 4 waves x 16 q-rows.  K/V tiles [64][64] shorts, XOR swizzle col^=(row&7)<<3,
// staged via global_load_lds (linear LDS dest, pre-swizzled global source).
// K/V fragment reads: inline-asm ds_read_b128 + lgkmcnt (no compiler vmcnt).
// ---------------------------------------------------------------------------
__global__ __launch_bounds__(256) void attn_k(
    const short* __restrict__ Q, const short* __restrict__ Kg,
    const short* __restrict__ Vtg, short* __restrict__ out) {
    __shared__ __attribute__((aligned(128))) short Kl[2][64 * 64];
    __shared__ __attribute__((aligned(128))) short Vl[2][64 * 64];
    __shared__ __attribute__((aligned(128))) short Pl[4][16 * 64];
    const int tid = threadIdx.x, lane = tid & 63, w = tid >> 6;
    // XCD chunk swizzle: 1536 blocks = 8 XCDs x 192.
    const int swz = (blockIdx.x & 7) * 192 + (blockIdx.x >> 3);
    const int qt = swz & 15, bh = swz >> 4;
    const int b = bh / 12, h = bh % 12;
    const int q0 = qt * 64 + w * 16;
    const int l15 = lane & 15, g = lane >> 4;

    // Q fragments (A-operand); Q already scaled by 1/sqrt(HD).
    bf16x8 aq[2];
    const short* Qb = Q + ((size_t)bh * 1024 + q0) * 64;
#pragma unroll
    for (int kk = 0; kk < 2; ++kk)
        aq[kk] = *(const bf16x8*)&Qb[(size_t)l15 * 64 + kk * 32 + g * 8];

    float m_run[4], l_run[4];
    f32x4 o[4] = {};
#pragma unroll
    for (int r = 0; r < 4; ++r) { m_run[r] = -1e30f; l_run[r] = 0.f; }

    const short* Kb = Kg + (size_t)bh * 1024 * 64;   // [S][64]
    const short* Vb = Vtg + (size_t)bh * 64 * 1024;  // [64][S]

    // ---- staging addresses: linear LDS dest, pre-swizzled global col ----
    const int srr = tid >> 3;               // 0..31 (row within sweep)
    const int spp = (tid & 7) * 8;          // col shorts (linear dest)
    const int ssc = spp ^ ((srr & 7) << 3); // swizzled source col
    auto stage = [&](int buf, int kv0) {
        gload_lds16(Kb + (size_t)(kv0 + srr) * 64 + ssc,      &Kl[buf][w * 512]);
        gload_lds16(Kb + (size_t)(kv0 + 32 + srr) * 64 + ssc, &Kl[buf][2048 + w * 512]);
        gload_lds16(Vb + (size_t)srr * 1024 + kv0 + ssc,      &Vl[buf][w * 512]);
        gload_lds16(Vb + (size_t)(srr + 32) * 1024 + kv0 + ssc, &Vl[buf][2048 + w * 512]);
    };

    stage(0, 0);
    __syncthreads();

    int buf = 0;
    for (int t = 0; t < 16; ++t) {
        const lds_cp KB = (lds_cp)&Kl[buf][0];
        const lds_cp VB = (lds_cp)&Vl[buf][0];

        // K fragments (asm ds_read)
        bf16x8 kb[4][2];
#pragma unroll
        for (int nk = 0; nk < 4; ++nk) {
            const int R = nk * 16 + l15;
            const int c0 = (g * 8) ^ ((R & 7) << 3);
            const lds_cp a0 = KB + R * 128 + c0 * 2;
            const lds_cp a1 = KB + R * 128 + (c0 ^ 32) * 2;
            DSR(kb[nk][0], a0, 0);
            DSR(kb[nk][1], a1, 0);
        }

        // prefetch next K/V tile (vmcnt only; drained by end-of-tile barrier)
        if (t < 15) stage(buf ^ 1, (t + 1) * 64);

        WAITLG;  // K frags in VGPRs
        SCHEDB;

        f32x4 sc4[4];
#pragma unroll
        for (int nk = 0; nk < 4; ++nk) {
            f32x4 z = {};
            z = MFMA16(aq[0], kb[nk][0], z);
            z = MFMA16(aq[1], kb[nk][1], z);
            sc4[nk] = z;
        }

        // online softmax (row = g*4 + r; 16 cols across lanes of group)
        float alpha[4], padd[4][4];
#pragma unroll
        for (int r = 0; r < 4; ++r) {
            float ml = fmaxf(fmaxf(sc4[0][r], sc4[1][r]), fmaxf(sc4[2][r], sc4[3][r]));
#pragma unroll
            for (int mk = 1; mk <= 8; mk <<= 1) ml = fmaxf(ml, __shfl_xor(ml, mk));
            const float mn = fmaxf(m_run[r], ml);
            alpha[r] = __expf(m_run[r] - mn);
            m_run[r] = mn;
            float rsum = 0.f;
#pragma unroll
            for (int nk = 0; nk < 4; ++nk) {
                padd[nk][r] = __expf(sc4[nk][r] - mn);
                rsum += padd[nk][r];
            }
#pragma unroll
            for (int mk = 1; mk <= 8; mk <<= 1) rsum += __shfl_xor(rsum, mk);
            l_run[r] = l_run[r] * alpha[r] + rsum;
#pragma unroll
            for (int dn = 0; dn < 4; ++dn) o[dn][r] *= alpha[r];
        }

        // P (C-layout) -> per-wave LDS -> A-layout fragments (normal ops; Pl
        // is a distinct LDS object, untouched by global_load_lds)
#pragma unroll
        for (int nk = 0; nk < 4; ++nk)
#pragma unroll
            for (int r = 0; r < 4; ++r) {
                const int rr = g * 4 + r, cc = nk * 16 + l15;
                Pl[w][rr * 64 + (cc ^ ((rr & 7) << 3))] = f2bf(padd[nk][r]);
            }
        bf16x8 pa[2];
#pragma unroll
        for (int kk = 0; kk < 2; ++kk)
            pa[kk] = *(const bf16x8*)&Pl[w][l15 * 64 + ((kk * 32 + g * 8) ^ ((l15 & 7) << 3))];

        // V fragments (asm ds_read)
        bf16x8 vb[4][2];
#pragma unroll
        for (int dn = 0; dn < 4; ++dn) {
            const int R = dn * 16 + l15;
            const int c0 = (g * 8) ^ ((R & 7) << 3);
            const lds_cp a0 = VB + R * 128 + c0 * 2;
            const lds_cp a1 = VB + R * 128 + (c0 ^ 32) * 2;
            DSR(vb[dn][0], a0, 0);
            DSR(vb[dn][1], a1, 0);
        }
        WAITLG;  // V frags (and P reads) complete
        SCHEDB;

#pragma unroll
        for (int dn = 0; dn < 4; ++dn) {
            o[dn] = MFMA16(pa[0], vb[dn][0], o[dn]);
            o[dn] = MFMA16(pa[1], vb[dn][1], o[dn]);
        }

        __syncthreads();  // drains stage(t+1) vmcnt; guards buf WAR
        buf ^= 1;
    }

    // normalize + write attn output as [B,S,H] bf16
#pragma unroll
    for (int r = 0; r < 4; ++r) {
        const float rl = __builtin_amdgcn_rcpf(l_run[r]);
        const int srow = q0 + g * 4 + r;
#pragma unroll
        for (int dn = 0; dn < 4; ++dn)
            out[((size_t)(b * 1024) + srow) * 768 + h * 64 + dn * 16 + l15] =
                f2bf(o[dn][r] * rl);
    }
}

// ---------------------------------------------------------------------------
// Launch
// ---------------------------------------------------------------------------
extern "C" void kernel_launch(void* const* d_in, const int* in_sizes, int n_in,
                              void* d_out, int out_size, void* d_ws, size_t ws_size,
                              hipStream_t stream) {
    const float* x      = (const float*)d_in[0];
    const float* ln1_g  = (const float*)d_in[1];
    const float* ln1_b  = (const float*)d_in[2];
    const float* qkv_w  = (const float*)d_in[3];
    const float* qkv_b  = (const float*)d_in[4];
    const float* proj_w = (const float*)d_in[5];
    const float* proj_b = (const float*)d_in[6];
    const float* ln2_g  = (const float*)d_in[7];
    const float* ln2_b  = (const float*)d_in[8];
    const float* fc1_w  = (const float*)d_in[9];
    const float* fc1_b  = (const float*)d_in[10];
    const float* fc2_w  = (const float*)d_in[11];
    const float* fc2_b  = (const float*)d_in[12];
    float* outp = (float*)d_out;

    char* ws = (char*)d_ws;
    size_t off = 0;
    auto alloc = [&](size_t bytes) {
        char* p = ws + off;
        off = (off + bytes + 255) & ~(size_t)255;
        return p;
    };
    short* wt_qkv  = (short*)alloc(2304ull * 768 * 2);
    short* wt_proj = (short*)alloc(768ull * 768 * 2);
    short* wt_fc1  = (short*)alloc(3072ull * 768 * 2);
    short* wt_fc2  = (short*)alloc(768ull * 3072 * 2);
    short* hbuf    = (short*)alloc(8192ull * 768 * 2);
    short* Qb      = (short*)alloc(8192ull * 768 * 2);   // [B,NH,S,HD]
    short* Kbuf    = (short*)alloc(8192ull * 768 * 2);   // [B,NH,S,HD]
    short* Vtb     = (short*)alloc(8192ull * 768 * 2);   // [B,NH,HD,S]
    short* attnb   = (short*)alloc(8192ull * 768 * 2);   // [B,S,H]
    float* x2      = (float*)alloc(8192ull * 768 * 4);   // fp32 residual stream
    short* mfc     = Qb;  // alias: fc1 output [8192,3072] over dead Q/K/Vt/attn
    (void)ws_size; (void)in_sizes; (void)n_in; (void)out_size;

    // weight prep
    transpose_w<<<dim3(2304 / 32, 768 / 32), 256, 0, stream>>>(qkv_w, wt_qkv, 768, 2304);
    transpose_w<<<dim3(768 / 32, 768 / 32), 256, 0, stream>>>(proj_w, wt_proj, 768, 768);
    transpose_w<<<dim3(3072 / 32, 768 / 32), 256, 0, stream>>>(fc1_w, wt_fc1, 768, 3072);
    transpose_w<<<dim3(768 / 32, 3072 / 32), 256, 0, stream>>>(fc2_w, wt_fc2, 3072, 768);

    // attention sublayer
    ln_k<<<8192, 256, 0, stream>>>(x, ln1_g, ln1_b, hbuf);
    gemm3p<MODE_QKV><<<dim3(64, 18), 256, 0, stream>>>(
        hbuf, wt_qkv, qkv_b, nullptr, nullptr, nullptr, Qb, Kbuf, Vtb, 8192, 2304, 768);
    attn_k<<<1536, 256, 0, stream>>>(Qb, Kbuf, Vtb, attnb);
    gemm3p<MODE_F32RES><<<dim3(64, 6), 256, 0, stream>>>(
        attnb, wt_proj, proj_b, x, x2, nullptr, nullptr, nullptr, nullptr, 8192, 768, 768);

    // MLP sublayer
    ln_k<<<8192, 256, 0, stream>>>(x2, ln2_g, ln2_b, hbuf);
    gemm3p<MODE_GELU><<<dim3(64, 24), 256, 0, stream>>>(
        hbuf, wt_fc1, fc1_b, nullptr, nullptr, mfc, nullptr, nullptr, nullptr, 8192, 3072, 768);
    gemm3p<MODE_F32RES><<<dim3(64, 6), 256, 0, stream>>>(
        mfc, wt_fc2, fc2_b, x2, outp, nullptr, nullptr, nullptr, nullptr, 8192, 768, 3072);
}

// Round 8
// 280.322 us; speedup vs baseline: 1.5004x; 1.1009x over previous
//
#include <hip/hip_runtime.h>
#include <hip/hip_bf16.h>

// ---------------------------------------------------------------------------
// Transformer block, B=8 S=1024 H=768 NH=12 HD=64 I=3072.  fp32 in/out,
// bf16 MFMA internals.
// Round 8: attn softmax restructured via SWAPPED operands (T12 mechanism):
//   S^T = mfma(K,Q)  -> each lane owns one q-row's scores (16 kv values)
//     => row-reduce = 15 lane-local fmax + 2 shuffles (was 32 shuffles/tile),
//        m/l/alpha per-lane scalars (was x4 duplicated).
//   P packed with v_cvt_pk_bf16_f32 -> 4 ds_write_b64 (was 16 ds_write_b16).
//   O^T = mfma(V^T,P^T) with the SAME register fragments -> O columns = own q,
//        scalar rescale/normalize, packed 8B epilogue stores.
// Staging/swizzles/XCD mapping and GEMM engine unchanged (round 4/6).
// ---------------------------------------------------------------------------

typedef __attribute__((ext_vector_type(8))) short bf16x8;
typedef __attribute__((ext_vector_type(4))) float f32x4;
typedef const __attribute__((address_space(3))) char* lds_cp;

#define MFMA16(a, b, c) __builtin_amdgcn_mfma_f32_16x16x32_bf16((a), (b), (c), 0, 0, 0)

// inline-asm LDS read: invisible to compiler alias analysis (no auto-vmcnt).
#define DSR(dst, addr, off) \
    asm volatile("ds_read_b128 %0, %1 offset:" #off : "=v"(dst) : "v"(addr))
#define WAITV4 asm volatile("s_waitcnt vmcnt(4)" ::: "memory")
#define WAITV0 asm volatile("s_waitcnt vmcnt(0)" ::: "memory")
#define WAITLG asm volatile("s_waitcnt lgkmcnt(0)" ::: "memory")
#define SCHEDB __builtin_amdgcn_sched_barrier(0)
// packed f32x2 -> bf16x2 (RNE), single instruction
#define CVTPK(d, lo, hi) \
    asm("v_cvt_pk_bf16_f32 %0, %1, %2" : "=v"(d) : "v"(lo), "v"(hi))

__device__ inline short f2bf(float x) {
    __hip_bfloat16 h = __float2bfloat16(x);
    return *reinterpret_cast<short*>(&h);
}

__device__ inline void gload_lds16(const void* g, void* lds) {
    __builtin_amdgcn_global_load_lds(
        (const __attribute__((address_space(1))) unsigned int*)g,
        (__attribute__((address_space(3))) unsigned int*)lds,
        16, 0, 0);
}

// ---------------------------------------------------------------------------
// Weight prep: W fp32 [K,N] -> Wt bf16 [N,K]   (tiled transpose + cast)
// ---------------------------------------------------------------------------
__global__ __launch_bounds__(256) void transpose_w(
    const float* __restrict__ W, short* __restrict__ Wt, int K, int N) {
    __shared__ float tile[32][33];
    const int tx = threadIdx.x & 31, ty = threadIdx.x >> 5;  // ty 0..7
    const int n0 = blockIdx.x * 32, k0 = blockIdx.y * 32;
#pragma unroll
    for (int i = 0; i < 4; ++i)
        tile[ty + i * 8][tx] = W[(size_t)(k0 + ty + i * 8) * N + n0 + tx];
    __syncthreads();
#pragma unroll
    for (int i = 0; i < 4; ++i)
        Wt[(size_t)(n0 + ty + i * 8) * K + k0 + tx] = f2bf(tile[tx][ty + i * 8]);
}

// ---------------------------------------------------------------------------
// LayerNorm: fp32 [M,768] -> bf16 [M,768]   (one block per row)
// ---------------------------------------------------------------------------
__global__ __launch_bounds__(256) void ln_k(
    const float* __restrict__ x, const float* __restrict__ g,
    const float* __restrict__ b, short* __restrict__ out) {
    const int row = blockIdx.x;
    const int tid = threadIdx.x;
    const float* xr = x + (size_t)row * 768;
    float v[3];
    float s = 0.f, sq = 0.f;
#pragma unroll
    for (int i = 0; i < 3; ++i) {
        v[i] = xr[tid + i * 256];
        s += v[i];
        sq += v[i] * v[i];
    }
#pragma unroll
    for (int off = 32; off >= 1; off >>= 1) {
        s += __shfl_xor(s, off);
        sq += __shfl_xor(sq, off);
    }
    __shared__ float ss[4], ssq[4];
    const int wid = tid >> 6;
    if ((tid & 63) == 0) { ss[wid] = s; ssq[wid] = sq; }
    __syncthreads();
    s = ss[0] + ss[1] + ss[2] + ss[3];
    sq = ssq[0] + ssq[1] + ssq[2] + ssq[3];
    const float mean = s * (1.0f / 768.0f);
    const float var = sq * (1.0f / 768.0f) - mean * mean;  // biased
    const float rstd = rsqrtf(var + 1e-5f);
    short* outr = out + (size_t)row * 768;
#pragma unroll
    for (int i = 0; i < 3; ++i) {
        const int c = tid + i * 256;
        outr[c] = f2bf((v[i] - mean) * rstd * g[c] + b[c]);
    }
}

// ---------------------------------------------------------------------------
// GEMM engine:  C[M,N] = A[M,K](bf16) @ Wt[N,K]^T(bf16) + bias, fused epilogues.
// 128x128 tile, BK=32, 4 waves (2x2), wave = 64x64 out (4x4 16x16 frags).
// (unchanged from round 4)
// ---------------------------------------------------------------------------
enum { MODE_BF16 = 0, MODE_QKV = 1, MODE_F32RES = 2, MODE_GELU = 3 };

template <int MODE>
__global__ __launch_bounds__(256) void gemm3p(
    const short* __restrict__ A, const short* __restrict__ Wt,
    const float* __restrict__ bias, const float* __restrict__ resid,
    float* __restrict__ outf, short* __restrict__ outh,
    short* __restrict__ Qo, short* __restrict__ Ko, short* __restrict__ Vto,
    int M, int N, int K) {
    __shared__ __attribute__((aligned(128))) short Al[3][4096];  // [buf][128*32]
    __shared__ __attribute__((aligned(128))) short Bl[3][4096];
    const int tid = threadIdx.x;
    const int lane = tid & 63;
    const int w = tid >> 6;          // 4 waves
    const int wm = w >> 1, wn = w & 1;
    const int m0 = blockIdx.x * 128, n0 = blockIdx.y * 128;

    f32x4 acc[4][4] = {};

    // ---- staging: linear LDS dest, pre-swizzled global source ----
    const int srow = tid >> 2;
    const int scol = ((tid & 3) * 8) ^ (((tid >> 2) & 3) << 3);
    const short* Abase = A + (size_t)(m0 + srow) * K + scol;
    const short* Bbase = Wt + (size_t)(n0 + srow) * K + scol;
    const size_t K64 = (size_t)K * 64;
    short* const AlF = &Al[0][0];
    short* const BlF = &Bl[0][0];

    auto stageT = [&](int boS, int k0s) {  // boS: buffer offset in shorts
        gload_lds16(Abase + k0s,       AlF + boS + w * 512);
        gload_lds16(Abase + K64 + k0s, AlF + boS + 2048 + w * 512);
        gload_lds16(Bbase + k0s,       BlF + boS + w * 512);
        gload_lds16(Bbase + K64 + k0s, BlF + boS + 2048 + w * 512);
    };

    // ---- fragment read offsets (swizzled), bytes within one buffer ----
    const int lrow = lane & 15;
    const int lcolswz = ((lane >> 4) * 16) ^ ((lane & 3) << 4);
    const int aoff = wm * 4096 + lrow * 64 + lcolswz;
    const int boff = wn * 4096 + lrow * 64 + lcolswz;
    const lds_cp AlB = (lds_cp)AlF;
    const lds_cp BlB = (lds_cp)BlF;

    const int NT = K >> 5;

    // prologue: stage tiles 0,1; retire tile 0; collective barrier
    stageT(0, 0);
    stageT(4096, 32);
    WAITV4;
    SCHEDB;
    __builtin_amdgcn_s_barrier();

    int bo = 0, bo1 = 8192, bo2 = 16384;  // byte offsets of buffers t, t+1, t+2
    for (int t = 0; t < NT; ++t) {
        const lds_cp Ab = AlB + (bo + aoff);
        const lds_cp Bb = BlB + (bo + boff);
        bf16x8 av0, av1, av2, av3, bv0, bv1, bv2, bv3;
        DSR(av0, Ab, 0);
        DSR(av1, Ab, 1024);
        DSR(av2, Ab, 2048);
        DSR(av3, Ab, 3072);
        DSR(bv0, Bb, 0);
        DSR(bv1, Bb, 1024);
        DSR(bv2, Bb, 2048);
        DSR(bv3, Bb, 3072);

        int ts = t + 2;
        if (ts > NT - 1) ts = NT - 1;      // uniform dummy stage at tail
        stageT(bo2 >> 1, ts << 5);
        WAITV4;                             // tile t+1 landed; t+2 in flight
        SCHEDB;
        __builtin_amdgcn_s_barrier();
        WAITLG;                             // frags in VGPRs
        SCHEDB;                             // rule #18: pin MFMA after the wait

        __builtin_amdgcn_s_setprio(1);
        {
            bf16x8 av[4] = {av0, av1, av2, av3};
            bf16x8 bv[4] = {bv0, bv1, bv2, bv3};
#pragma unroll
            for (int mi = 0; mi < 4; ++mi)
#pragma unroll
                for (int ni = 0; ni < 4; ++ni)
                    acc[mi][ni] = MFMA16(av[mi], bv[ni], acc[mi][ni]);
        }
        __builtin_amdgcn_s_setprio(0);
        __builtin_amdgcn_s_barrier();

        const int tmp = bo; bo = bo1; bo1 = bo2; bo2 = tmp;
    }
    WAITV0;  // drain dummy stages before epilogue/endpgm

    // Epilogue.  C/D frag layout: col = lane&15, row = (lane>>4)*4 + r.
#pragma unroll
    for (int mi = 0; mi < 4; ++mi) {
#pragma unroll
        for (int ni = 0; ni < 4; ++ni) {
#pragma unroll
            for (int r = 0; r < 4; ++r) {
                const int row = m0 + wm * 64 + mi * 16 + (lane >> 4) * 4 + r;
                const int col = n0 + wn * 64 + ni * 16 + (lane & 15);
                float v = acc[mi][ni][r] + bias[col];
                if constexpr (MODE == MODE_BF16) {
                    outh[(size_t)row * N + col] = f2bf(v);
                } else if constexpr (MODE == MODE_GELU) {
                    // 0.5v(1+tanh(u)) == v*sigmoid(2u)
                    const float u = 0.7978845608028654f * (v + 0.044715f * v * v * v);
                    const float gl = v / (1.0f + __expf(-2.0f * u));
                    outh[(size_t)row * N + col] = f2bf(gl);
                } else if constexpr (MODE == MODE_F32RES) {
                    outf[(size_t)row * N + col] = v + resid[(size_t)row * N + col];
                } else {  // MODE_QKV: scatter into Q[B,NH,S,HD] (pre-scaled by
                          // 1/sqrt(HD)), K[B,NH,S,HD], Vt[B,NH,HD,S]
                    const int bb = row >> 10, s = row & 1023;
                    if (col < 768) {
                        const int hh = col >> 6, d = col & 63;
                        Qo[(((size_t)(bb * 12 + hh)) * 1024 + s) * 64 + d] = f2bf(v * 0.125f);
                    } else if (col < 1536) {
                        const int c2 = col - 768;
                        const int hh = c2 >> 6, d = c2 & 63;
                        Ko[(((size_t)(bb * 12 + hh)) * 1024 + s) * 64 + d] = f2bf(v);
                    } else {
                        const int c2 = col - 1536;
                        const int hh = c2 >> 6, d = c2 & 63;
                        Vto[(((size_t)(bb * 12 + hh)) * 64 + d) * 1024 + s] = f2bf(v);
                    }
                }
            }
        }
    }
}

// ---------------------------------------------------------------------------
// Flash attention, swapped-operand softmax.
// Grid: B*NH*16 blocks, XCD-swizzled (each XCD owns 12 whole heads).
// 4 waves x 16 q-rows.  K/V tiles [64][64] shorts, XOR swizzle col^=(row&7)<<3,
// double-buffered via global_load_lds; 1 barrier per tile.
// S^T = mfma(K,Q): lane owns q = lane&15, kv = nk*16 + g*4 + r.
// O^T = mfma(V^T,P^T): lane owns q = lane&15, d = dn*16 + g*4 + r.
// ---------------------------------------------------------------------------
__global__ __launch_bounds__(256) void attn_k(
    const short* __restrict__ Q, const short* __restrict__ Kg,
    const short* __restrict__ Vtg, short* __restrict__ out) {
    __shared__ __attribute__((aligned(128))) short Kl[2][64 * 64];
    __shared__ __attribute__((aligned(128))) short Vl[2][64 * 64];
    __shared__ __attribute__((aligned(128))) short Pl[4][16 * 64];
    const int tid = threadIdx.x, lane = tid & 63, w = tid >> 6;
    // XCD chunk swizzle: 1536 blocks = 8 XCDs x 192.
    const int swz = (blockIdx.x & 7) * 192 + (blockIdx.x >> 3);
    const int qt = swz & 15, bh = swz >> 4;
    const int b = bh / 12, h = bh % 12;
    const int q0 = qt * 64 + w * 16;
    const int l15 = lane & 15, g = lane >> 4;

    // Q fragments (pre-scaled by 1/sqrt(HD)): Q[q=l15][d = kk*32 + g*8 + j]
    bf16x8 aq[2];
    const short* Qb = Q + ((size_t)bh * 1024 + q0) * 64;
#pragma unroll
    for (int kk = 0; kk < 2; ++kk)
        aq[kk] = *(const bf16x8*)&Qb[(size_t)l15 * 64 + kk * 32 + g * 8];

    float m_run = -1e30f, l_run = 0.f;  // per-lane scalars (q = l15)
    f32x4 o[4] = {};                     // O^T: o[dn][r] = O[d=dn*16+g*4+r][q=l15]

    const short* Kb = Kg + (size_t)bh * 1024 * 64;   // [S][64]
    const short* Vb = Vtg + (size_t)bh * 64 * 1024;  // [64][S]

    // ---- staging addresses: linear LDS dest, pre-swizzled global col ----
    const int srr = tid >> 3;               // 0..31
    const int spp = (tid & 7) * 8;          // col shorts (linear dest)
    const int ssc = spp ^ ((srr & 7) << 3); // swizzled source col
    auto stage = [&](int buf, int kv0) {
        gload_lds16(Kb + (size_t)(kv0 + srr) * 64 + ssc,        &Kl[buf][w * 512]);
        gload_lds16(Kb + (size_t)(kv0 + 32 + srr) * 64 + ssc,   &Kl[buf][2048 + w * 512]);
        gload_lds16(Vb + (size_t)srr * 1024 + kv0 + ssc,        &Vl[buf][w * 512]);
        gload_lds16(Vb + (size_t)(srr + 32) * 1024 + kv0 + ssc, &Vl[buf][2048 + w * 512]);
    };

    stage(0, 0);
    __syncthreads();

    int buf = 0;
    for (int t = 0; t < 16; ++t) {
        const lds_cp KB = (lds_cp)&Kl[buf][0];
        const lds_cp VB = (lds_cp)&Vl[buf][0];

        // K fragments (asm ds_read): K[kv = nk*16 + l15][d slice]
        bf16x8 kb[4][2];
#pragma unroll
        for (int nk = 0; nk < 4; ++nk) {
            const int R = nk * 16 + l15;
            const int c0 = (g * 8) ^ ((R & 7) << 3);
            const lds_cp a0 = KB + R * 128 + c0 * 2;
            const lds_cp a1 = KB + R * 128 + (c0 ^ 32) * 2;
            DSR(kb[nk][0], a0, 0);
            DSR(kb[nk][1], a1, 0);
        }

        // prefetch next K/V tile (drained by end-of-tile barrier)
        if (t < 15) stage(buf ^ 1, (t + 1) * 64);

        WAITLG;  // K frags in VGPRs
        SCHEDB;

        // S^T = K·Q^T: sc4[nk][r] = S[kv = nk*16+g*4+r][q = l15]
        f32x4 sc4[4];
#pragma unroll
        for (int nk = 0; nk < 4; ++nk) {
            f32x4 z = {};
            z = MFMA16(kb[nk][0], aq[0], z);
            z = MFMA16(kb[nk][1], aq[1], z);
            sc4[nk] = z;
        }

        // online softmax: lane-local over 16 kv, then xor16/xor32 across g
        float ml = sc4[0][0];
#pragma unroll
        for (int nk = 0; nk < 4; ++nk)
#pragma unroll
            for (int r = 0; r < 4; ++r) ml = fmaxf(ml, sc4[nk][r]);
        ml = fmaxf(ml, __shfl_xor(ml, 16));
        ml = fmaxf(ml, __shfl_xor(ml, 32));
        const float mn = fmaxf(m_run, ml);
        const float alpha = __expf(m_run - mn);
        m_run = mn;
        float padd[4][4];
        float rsum = 0.f;
#pragma unroll
        for (int nk = 0; nk < 4; ++nk)
#pragma unroll
            for (int r = 0; r < 4; ++r) {
                padd[nk][r] = __expf(sc4[nk][r] - mn);
                rsum += padd[nk][r];
            }
        rsum += __shfl_xor(rsum, 16);
        rsum += __shfl_xor(rsum, 32);
        l_run = l_run * alpha + rsum;
#pragma unroll
        for (int dn = 0; dn < 4; ++dn) o[dn] *= alpha;

        // P pack: cvt_pk pairs -> ds_write_b64 at P[q=l15][kv=nk*16+g*4] (swz)
#pragma unroll
        for (int nk = 0; nk < 4; ++nk) {
            unsigned u0, u1;
            CVTPK(u0, padd[nk][0], padd[nk][1]);
            CVTPK(u1, padd[nk][2], padd[nk][3]);
            const int cc = (nk * 16 + g * 4) ^ ((l15 & 7) << 3);
            uint2 uv; uv.x = u0; uv.y = u1;
            *reinterpret_cast<uint2*>(&Pl[w][l15 * 64 + cc]) = uv;
        }
        // P^T B-frags = P[q=l15][kv slice] (same-wave RAW; compiler orders)
        bf16x8 pa[2];
#pragma unroll
        for (int kk = 0; kk < 2; ++kk)
            pa[kk] = *(const bf16x8*)&Pl[w][l15 * 64 + ((kk * 32 + g * 8) ^ ((l15 & 7) << 3))];

        // V^T A-frags (asm ds_read): Vt[d = dn*16 + l15][kv slice]
        bf16x8 vb[4][2];
#pragma unroll
        for (int dn = 0; dn < 4; ++dn) {
            const int R = dn * 16 + l15;
            const int c0 = (g * 8) ^ ((R & 7) << 3);
            const lds_cp a0 = VB + R * 128 + c0 * 2;
            const lds_cp a1 = VB + R * 128 + (c0 ^ 32) * 2;
            DSR(vb[dn][0], a0, 0);
            DSR(vb[dn][1], a1, 0);
        }
        WAITLG;  // V frags (and P reads) complete
        SCHEDB;

        // O^T += V^T · P^T
#pragma unroll
        for (int dn = 0; dn < 4; ++dn) {
            o[dn] = MFMA16(vb[dn][0], pa[0], o[dn]);
            o[dn] = MFMA16(vb[dn][1], pa[1], o[dn]);
        }

        __syncthreads();  // drains stage(t+1); guards buf WAR
        buf ^= 1;
    }

    // normalize + packed write: lane owns q = l15, d = dn*16 + g*4 + r
    const float rl = __builtin_amdgcn_rcpf(l_run);
    short* orow = out + ((size_t)(b * 1024) + q0 + l15) * 768 + h * 64;
#pragma unroll
    for (int dn = 0; dn < 4; ++dn) {
        unsigned u0, u1;
        const float v0 = o[dn][0] * rl, v1 = o[dn][1] * rl;
        const float v2 = o[dn][2] * rl, v3 = o[dn][3] * rl;
        CVTPK(u0, v0, v1);
        CVTPK(u1, v2, v3);
        uint2 uv; uv.x = u0; uv.y = u1;
        *reinterpret_cast<uint2*>(&orow[dn * 16 + g * 4]) = uv;
    }
}

// ---------------------------------------------------------------------------
// Launch
// ---------------------------------------------------------------------------
extern "C" void kernel_launch(void* const* d_in, const int* in_sizes, int n_in,
                              void* d_out, int out_size, void* d_ws, size_t ws_size,
                              hipStream_t stream) {
    const float* x      = (const float*)d_in[0];
    const float* ln1_g  = (const float*)d_in[1];
    const float* ln1_b  = (const float*)d_in[2];
    const float* qkv_w  = (const float*)d_in[3];
    const float* qkv_b  = (const float*)d_in[4];
    const float* proj_w = (const float*)d_in[5];
    const float* proj_b = (const float*)d_in[6];
    const float* ln2_g  = (const float*)d_in[7];
    const float* ln2_b  = (const float*)d_in[8];
    const float* fc1_w  = (const float*)d_in[9];
    const float* fc1_b  = (const float*)d_in[10];
    const float* fc2_w  = (const float*)d_in[11];
    const float* fc2_b  = (const float*)d_in[12];
    float* outp = (float*)d_out;

    char* ws = (char*)d_ws;
    size_t off = 0;
    auto alloc = [&](size_t bytes) {
        char* p = ws + off;
        off = (off + bytes + 255) & ~(size_t)255;
        return p;
    };
    short* wt_qkv  = (short*)alloc(2304ull * 768 * 2);
    short* wt_proj = (short*)alloc(768ull * 768 * 2);
    short* wt_fc1  = (short*)alloc(3072ull * 768 * 2);
    short* wt_fc2  = (short*)alloc(768ull * 3072 * 2);
    short* hbuf    = (short*)alloc(8192ull * 768 * 2);
    short* Qb      = (short*)alloc(8192ull * 768 * 2);   // [B,NH,S,HD]
    short* Kbuf    = (short*)alloc(8192ull * 768 * 2);   // [B,NH,S,HD]
    short* Vtb     = (short*)alloc(8192ull * 768 * 2);   // [B,NH,HD,S]
    short* attnb   = (short*)alloc(8192ull * 768 * 2);   // [B,S,H]
    float* x2      = (float*)alloc(8192ull * 768 * 4);   // fp32 residual stream
    short* mfc     = Qb;  // alias: fc1 output [8192,3072] over dead Q/K/Vt/attn
    (void)ws_size; (void)in_sizes; (void)n_in; (void)out_size;

    // weight prep
    transpose_w<<<dim3(2304 / 32, 768 / 32), 256, 0, stream>>>(qkv_w, wt_qkv, 768, 2304);
    transpose_w<<<dim3(768 / 32, 768 / 32), 256, 0, stream>>>(proj_w, wt_proj, 768, 768);
    transpose_w<<<dim3(3072 / 32, 768 / 32), 256, 0, stream>>>(fc1_w, wt_fc1, 768, 3072);
    transpose_w<<<dim3(768 / 32, 3072 / 32), 256, 0, stream>>>(fc2_w, wt_fc2, 3072, 768);

    // attention sublayer
    ln_k<<<8192, 256, 0, stream>>>(x, ln1_g, ln1_b, hbuf);
    gemm3p<MODE_QKV><<<dim3(64, 18), 256, 0, stream>>>(
        hbuf, wt_qkv, qkv_b, nullptr, nullptr, nullptr, Qb, Kbuf, Vtb, 8192, 2304, 768);
    attn_k<<<1536, 256, 0, stream>>>(Qb, Kbuf, Vtb, attnb);
    gemm3p<MODE_F32RES><<<dim3(64, 6), 256, 0, stream>>>(
        attnb, wt_proj, proj_b, x, x2, nullptr, nullptr, nullptr, nullptr, 8192, 768, 768);

    // MLP sublayer
    ln_k<<<8192, 256, 0, stream>>>(x2, ln2_g, ln2_b, hbuf);
    gemm3p<MODE_GELU><<<dim3(64, 24), 256, 0, stream>>>(
        hbuf, wt_fc1, fc1_b, nullptr, nullptr, mfc, nullptr, nullptr, nullptr, 8192, 3072, 768);
    gemm3p<MODE_F32RES><<<dim3(64, 6), 256, 0, stream>>>(
        mfc, wt_fc2, fc2_b, x2, outp, nullptr, nullptr, nullptr, nullptr, 8192, 768, 3072);
}